// Round 1
// baseline (212.521 us; speedup 1.0000x reference)
//
#include <hip/hip_runtime.h>
#include <hip/hip_bf16.h>
#include <stdint.h>

#define HID 1024
#define NH 16
#define HD 64
#define SEQ 2048
#define BATCH 2
#define M_TOT 4096

typedef __attribute__((ext_vector_type(8))) short short8;
typedef __attribute__((ext_vector_type(4))) float f32x4;
typedef __hip_bfloat16 bf16;

__device__ __forceinline__ void load_lds16(const void* g, void* l) {
  __builtin_amdgcn_global_load_lds(
      (const __attribute__((address_space(1))) unsigned int*)g,
      (__attribute__((address_space(3))) unsigned int*)l, 16, 0, 0);
}

__device__ __forceinline__ unsigned short f2bf_bits(float f) {
  __hip_bfloat16 h = __float2bfloat16(f);
  return *reinterpret_cast<unsigned short*>(&h);
}

// ---------------- prep kernels ----------------
__global__ void cvt_f32_to_bf16(const float* __restrict__ in,
                                bf16* __restrict__ out, int n4) {
  int i = blockIdx.x * blockDim.x + threadIdx.x;
  if (i >= n4) return;
  float4 v = reinterpret_cast<const float4*>(in)[i];
  ushort4 o;
  o.x = f2bf_bits(v.x); o.y = f2bf_bits(v.y);
  o.z = f2bf_bits(v.z); o.w = f2bf_bits(v.w);
  reinterpret_cast<ushort4*>(out)[i] = o;
}

// W [K][N] f32 -> WT [N][K] bf16
__global__ void transpose_cvt(const float* __restrict__ W,
                              bf16* __restrict__ WT, int K, int N) {
  __shared__ float tile[32][33];
  int n0 = blockIdx.x * 32, k0 = blockIdx.y * 32;
  int tx = threadIdx.x, ty = threadIdx.y;  // 32 x 8
#pragma unroll
  for (int i = 0; i < 32; i += 8)
    tile[ty + i][tx] = W[(size_t)(k0 + ty + i) * N + n0 + tx];
  __syncthreads();
#pragma unroll
  for (int i = 0; i < 32; i += 8)
    WT[(size_t)(n0 + ty + i) * K + k0 + tx] = __float2bfloat16(tile[tx][ty + i]);
}

// ---------------- GEMM: C[M][N] = A[M][K] * BT[N][K]^T + bias ----------------
// 128x128 tile, BK=64, 4 waves (2x2), each wave 64x64 = 4x4 frags of 16x16x32.
// EPI 0: scatter to Q/K/VT bf16.  EPI 1: write f32 to Fo.
template <int EPI>
__global__ __launch_bounds__(256, 2)
void gemm128(const bf16* __restrict__ A, const bf16* __restrict__ BT,
             const float* __restrict__ bias,
             bf16* __restrict__ Qo, bf16* __restrict__ Ko, bf16* __restrict__ Vo,
             float* __restrict__ Fo) {
  const int Kdim = 1024;
  __shared__ bf16 As[128 * 64];
  __shared__ bf16 Bs[128 * 64];
  const int tid = threadIdx.x;
  const int wid = tid >> 6, lane = tid & 63;
  const int m0 = blockIdx.x * 128;
  const int n0 = blockIdx.y * 128;
  const int wrow = (wid >> 1) * 64, wcol = (wid & 1) * 64;

  f32x4 acc[4][4];
#pragma unroll
  for (int rb = 0; rb < 4; ++rb)
#pragma unroll
    for (int cb = 0; cb < 4; ++cb)
      acc[rb][cb] = (f32x4){0.f, 0.f, 0.f, 0.f};

  const int lr = lane >> 3;        // 0..7
  const int lc = (lane & 7) * 8;   // element col for staging
  const int fr = lane & 15, fk = (lane >> 4) * 8;

  for (int kt = 0; kt < Kdim / 64; ++kt) {
    __syncthreads();
#pragma unroll
    for (int t = 0; t < 4; ++t) {
      int i = wid * 4 + t;
      int row = i * 8 + lr;
      load_lds16(A + (size_t)(m0 + row) * Kdim + kt * 64 + lc, (char*)As + i * 1024);
      load_lds16(BT + (size_t)(n0 + row) * Kdim + kt * 64 + lc, (char*)Bs + i * 1024);
    }
    __syncthreads();

    short8 af[4][2], bf_[4][2];
#pragma unroll
    for (int rb = 0; rb < 4; ++rb)
#pragma unroll
      for (int kk = 0; kk < 2; ++kk) {
        af[rb][kk] = *(const short8*)&As[(wrow + rb * 16 + fr) * 64 + kk * 32 + fk];
        bf_[rb][kk] = *(const short8*)&Bs[(wcol + rb * 16 + fr) * 64 + kk * 32 + fk];
      }
#pragma unroll
    for (int rb = 0; rb < 4; ++rb)
#pragma unroll
      for (int cb = 0; cb < 4; ++cb)
#pragma unroll
        for (int kk = 0; kk < 2; ++kk)
          acc[rb][cb] = __builtin_amdgcn_mfma_f32_16x16x32_bf16(
              af[rb][kk], bf_[cb][kk], acc[rb][cb], 0, 0, 0);
  }

  const int fg = (lane >> 4) * 4;
  float bv[4];
#pragma unroll
  for (int cb = 0; cb < 4; ++cb) bv[cb] = bias[n0 + wcol + cb * 16 + fr];

  if (EPI == 0) {
#pragma unroll
    for (int rb = 0; rb < 4; ++rb) {
      int r0 = m0 + wrow + rb * 16 + fg;
#pragma unroll
      for (int cb = 0; cb < 4; ++cb) {
        int n = n0 + wcol + cb * 16 + fr;
        int part = n >> 10;
        int d = n & 1023;
        int h = d >> 6, hd = d & 63;
#pragma unroll
        for (int j = 0; j < 4; ++j) {
          int m = r0 + j;
          int b = m >> 11, s = m & 2047;
          size_t bh = (size_t)(b * NH + h);
          bf16 val = __float2bfloat16(acc[rb][cb][j] + bv[cb]);
          if (part == 0)      Qo[(bh * SEQ + s) * HD + hd] = val;
          else if (part == 1) Ko[(bh * SEQ + s) * HD + hd] = val;
          else                Vo[(bh * HD + hd) * SEQ + s] = val;
        }
      }
    }
  } else {
#pragma unroll
    for (int rb = 0; rb < 4; ++rb) {
      int r0 = m0 + wrow + rb * 16 + fg;
#pragma unroll
      for (int cb = 0; cb < 4; ++cb) {
        int n = n0 + wcol + cb * 16 + fr;
#pragma unroll
        for (int j = 0; j < 4; ++j)
          Fo[(size_t)(r0 + j) * HID + n] = acc[rb][cb][j] + bv[cb];
      }
    }
  }
}

// ---------------- causal flash attention ----------------
// grid (SEQ/128, BATCH*NH), 256 thr. Wave w: q rows [qt*128+w*32, +32).
__global__ __launch_bounds__(256, 2)
void attn_kernel(const bf16* __restrict__ Q, const bf16* __restrict__ K,
                 const bf16* __restrict__ VT, bf16* __restrict__ ctx) {
  __shared__ bf16 Ks[64 * 64];
  __shared__ bf16 Vs[64 * 64];          // VT tile: [hd][s_local]
  __shared__ bf16 Ps[4][32 * 64];
  const int tid = threadIdx.x, wid = tid >> 6, lane = tid & 63;
  const int qt = blockIdx.x, bh = blockIdx.y;
  const int b = bh >> 4, h = bh & 15;
  const size_t base = (size_t)bh * SEQ * HD;
  const int q0 = qt * 128 + wid * 32;

  const int fr = lane & 15, fk = (lane >> 4) * 8, fg = (lane >> 4) * 4;
  const int lr = lane >> 3, lc = (lane & 7) * 8;

  short8 aq[2][2];
#pragma unroll
  for (int rb = 0; rb < 2; ++rb)
#pragma unroll
    for (int kk = 0; kk < 2; ++kk)
      aq[rb][kk] = *(const short8*)&Q[base + (size_t)(q0 + rb * 16 + fr) * HD + kk * 32 + fk];

  f32x4 octx[2][4];
  float mrow[2][4], lrow[2][4];
#pragma unroll
  for (int rb = 0; rb < 2; ++rb)
#pragma unroll
    for (int cb = 0; cb < 4; ++cb)
      octx[rb][cb] = (f32x4){0.f, 0.f, 0.f, 0.f};
#pragma unroll
  for (int rb = 0; rb < 2; ++rb)
#pragma unroll
    for (int j = 0; j < 4; ++j) { mrow[rb][j] = -__builtin_inff(); lrow[rb][j] = 0.f; }

  const int nkv = qt * 2 + 2;
  for (int kv = 0; kv < nkv; ++kv) {
    const int kv0 = kv * 64;
    __syncthreads();
#pragma unroll
    for (int t = 0; t < 2; ++t) {
      int i = wid * 2 + t;
      int row = i * 8 + lr;
      load_lds16(K + base + (size_t)(kv0 + row) * HD + lc, (char*)Ks + i * 1024);
      load_lds16(VT + base + (size_t)row * SEQ + kv0 + lc, (char*)Vs + i * 1024);
    }
    __syncthreads();
    if (kv0 > q0 + 31) continue;   // fully masked for this wave

    // S = Q K^T
    f32x4 sc[2][4];
#pragma unroll
    for (int rb = 0; rb < 2; ++rb)
#pragma unroll
      for (int cb = 0; cb < 4; ++cb)
        sc[rb][cb] = (f32x4){0.f, 0.f, 0.f, 0.f};
    short8 bk[4][2];
#pragma unroll
    for (int cb = 0; cb < 4; ++cb)
#pragma unroll
      for (int kk = 0; kk < 2; ++kk)
        bk[cb][kk] = *(const short8*)&Ks[(cb * 16 + fr) * 64 + kk * 32 + fk];
#pragma unroll
    for (int rb = 0; rb < 2; ++rb)
#pragma unroll
      for (int cb = 0; cb < 4; ++cb)
#pragma unroll
        for (int kk = 0; kk < 2; ++kk)
          sc[rb][cb] = __builtin_amdgcn_mfma_f32_16x16x32_bf16(
              aq[rb][kk], bk[cb][kk], sc[rb][cb], 0, 0, 0);

    // mask + online softmax
    float p[2][4][4];
#pragma unroll
    for (int rb = 0; rb < 2; ++rb) {
#pragma unroll
      for (int j = 0; j < 4; ++j) {
        int qr = q0 + rb * 16 + fg + j;
        float mx = -__builtin_inff();
#pragma unroll
        for (int cb = 0; cb < 4; ++cb) {
          int kc = kv0 + cb * 16 + fr;
          float s = (kc <= qr) ? sc[rb][cb][j] * 0.125f : -__builtin_inff();
          p[rb][cb][j] = s;
          mx = fmaxf(mx, s);
        }
#pragma unroll
        for (int off = 1; off < 16; off <<= 1) mx = fmaxf(mx, __shfl_xor(mx, off));
        float mnew = fmaxf(mrow[rb][j], mx);
        float msafe = (mnew == -__builtin_inff()) ? 0.f : mnew;
        float fac = __expf(mrow[rb][j] - msafe);
        mrow[rb][j] = mnew;
        float rsum = 0.f;
#pragma unroll
        for (int cb = 0; cb < 4; ++cb) {
          float e = __expf(p[rb][cb][j] - msafe);
          p[rb][cb][j] = e;
          rsum += e;
        }
#pragma unroll
        for (int off = 1; off < 16; off <<= 1) rsum += __shfl_xor(rsum, off);
        lrow[rb][j] = lrow[rb][j] * fac + rsum;
#pragma unroll
        for (int cb = 0; cb < 4; ++cb) octx[rb][cb][j] *= fac;
      }
    }

    // P -> LDS (per-wave region), then PV
    bf16* Pw = Ps[wid];
#pragma unroll
    for (int rb = 0; rb < 2; ++rb)
#pragma unroll
      for (int cb = 0; cb < 4; ++cb)
#pragma unroll
        for (int j = 0; j < 4; ++j)
          Pw[(rb * 16 + fg + j) * 64 + cb * 16 + fr] = __float2bfloat16(p[rb][cb][j]);

    short8 ap[2][2], bvv[4][2];
#pragma unroll
    for (int rb = 0; rb < 2; ++rb)
#pragma unroll
      for (int kk = 0; kk < 2; ++kk)
        ap[rb][kk] = *(const short8*)&Pw[(rb * 16 + fr) * 64 + kk * 32 + fk];
#pragma unroll
    for (int cb = 0; cb < 4; ++cb)
#pragma unroll
      for (int kk = 0; kk < 2; ++kk)
        bvv[cb][kk] = *(const short8*)&Vs[(cb * 16 + fr) * 64 + kk * 32 + fk];
#pragma unroll
    for (int rb = 0; rb < 2; ++rb)
#pragma unroll
      for (int cb = 0; cb < 4; ++cb)
#pragma unroll
        for (int kk = 0; kk < 2; ++kk)
          octx[rb][cb] = __builtin_amdgcn_mfma_f32_16x16x32_bf16(
              ap[rb][kk], bvv[cb][kk], octx[rb][cb], 0, 0, 0);
  }

  // epilogue: ctx[b*SEQ+s][h*64+hd] bf16
#pragma unroll
  for (int rb = 0; rb < 2; ++rb)
#pragma unroll
    for (int cb = 0; cb < 4; ++cb)
#pragma unroll
      for (int j = 0; j < 4; ++j) {
        int s = q0 + rb * 16 + fg + j;
        float o = octx[rb][cb][j] / lrow[rb][j];
        ctx[(size_t)(b * SEQ + s) * HID + h * 64 + cb * 16 + fr] = __float2bfloat16(o);
      }
}

// ---------------- launch ----------------
extern "C" void kernel_launch(void* const* d_in, const int* in_sizes, int n_in,
                              void* d_out, int out_size, void* d_ws, size_t ws_size,
                              hipStream_t stream) {
  const float* x      = (const float*)d_in[0];
  const float* W_attn = (const float*)d_in[1];
  const float* b_attn = (const float*)d_in[2];
  const float* W_proj = (const float*)d_in[3];
  const float* b_proj = (const float*)d_in[4];
  float* out = (float*)d_out;

  char* ws = (char*)d_ws;
  const size_t MB = 1u << 20;
  bf16* xb   = (bf16*)(ws + 0);        // 8 MiB  [4096][1024]
  bf16* WTa  = (bf16*)(ws + 8 * MB);   // 6 MiB  [3072][1024]
  bf16* WTp  = (bf16*)(ws + 14 * MB);  // 2 MiB  [1024][1024]
  bf16* Qw   = (bf16*)(ws + 16 * MB);  // 8 MiB  [2][16][2048][64]
  bf16* Kw   = (bf16*)(ws + 24 * MB);  // 8 MiB
  bf16* VTw  = (bf16*)(ws + 32 * MB);  // 8 MiB  [2][16][64][2048]
  bf16* ctxb = (bf16*)(ws + 40 * MB);  // 8 MiB  [4096][1024]

  cvt_f32_to_bf16<<<(M_TOT * HID / 4 + 255) / 256, 256, 0, stream>>>(x, xb, M_TOT * HID / 4);
  transpose_cvt<<<dim3(3 * HID / 32, HID / 32), dim3(32, 8), 0, stream>>>(W_attn, WTa, HID, 3 * HID);
  transpose_cvt<<<dim3(HID / 32, HID / 32), dim3(32, 8), 0, stream>>>(W_proj, WTp, HID, HID);

  gemm128<0><<<dim3(M_TOT / 128, 3 * HID / 128), 256, 0, stream>>>(
      xb, WTa, b_attn, Qw, Kw, VTw, nullptr);

  attn_kernel<<<dim3(SEQ / 128, BATCH * NH), 256, 0, stream>>>(Qw, Kw, VTw, ctxb);

  gemm128<1><<<dim3(M_TOT / 128, HID / 128), 256, 0, stream>>>(
      ctxb, WTp, b_proj, nullptr, nullptr, nullptr, out);
}

// Round 3
// 137.316 us; speedup vs baseline: 1.5477x; 1.5477x over previous
//
#include <hip/hip_runtime.h>
#include <hip/hip_bf16.h>
#include <stdint.h>

#define HID 1024
#define NH 16
#define HD 64
#define SEQ 2048
#define BATCH 2
#define M_TOT 4096
#define QSCALE 0.18033688011112042f  /* 0.125 * log2(e) */

typedef __attribute__((ext_vector_type(8))) short short8;
typedef __attribute__((ext_vector_type(4))) float f32x4;
typedef __attribute__((ext_vector_type(16))) float f32x16;
typedef __hip_bfloat16 bf16;

__device__ __forceinline__ void load_lds16(const void* g, void* l) {
  __builtin_amdgcn_global_load_lds(
      (const __attribute__((address_space(1))) unsigned int*)g,
      (__attribute__((address_space(3))) unsigned int*)l, 16, 0, 0);
}

__device__ __forceinline__ unsigned short f2bf_bits(float f) {
  __hip_bfloat16 h = __float2bfloat16(f);
  return *reinterpret_cast<unsigned short*>(&h);
}
__device__ __forceinline__ unsigned pack2bf(float a, float b) {
  return (unsigned)f2bf_bits(a) | ((unsigned)f2bf_bits(b) << 16);
}
__device__ __forceinline__ unsigned cvt_pk_bf16(float a, float b) {
  unsigned r;
  asm("v_cvt_pk_bf16_f32 %0, %1, %2" : "=v"(r) : "v"(a), "v"(b));
  return r;
}

// ---------------- prep kernels ----------------
__global__ void cvt_f32_to_bf16(const float* __restrict__ in,
                                bf16* __restrict__ out, int n4) {
  int i = blockIdx.x * blockDim.x + threadIdx.x;
  if (i >= n4) return;
  float4 v = reinterpret_cast<const float4*>(in)[i];
  ushort4 o;
  o.x = f2bf_bits(v.x); o.y = f2bf_bits(v.y);
  o.z = f2bf_bits(v.z); o.w = f2bf_bits(v.w);
  reinterpret_cast<ushort4*>(out)[i] = o;
}

__global__ void transpose_cvt(const float* __restrict__ W,
                              bf16* __restrict__ WT, int K, int N) {
  __shared__ float tile[32][33];
  int n0 = blockIdx.x * 32, k0 = blockIdx.y * 32;
  int tx = threadIdx.x, ty = threadIdx.y;  // 32 x 8
#pragma unroll
  for (int i = 0; i < 32; i += 8)
    tile[ty + i][tx] = W[(size_t)(k0 + ty + i) * N + n0 + tx];
  __syncthreads();
#pragma unroll
  for (int i = 0; i < 32; i += 8)
    WT[(size_t)(n0 + ty + i) * K + k0 + tx] = __float2bfloat16(tile[tx][ty + i]);
}

// ---------------- GEMM: C[M][N] = A[M][K] * BT[N][K]^T + bias ----------------
template <int EPI>
__global__ __launch_bounds__(256, 2)
void gemm128(const bf16* __restrict__ A, const bf16* __restrict__ BT,
             const float* __restrict__ bias,
             bf16* __restrict__ Qo, bf16* __restrict__ Ko, bf16* __restrict__ Vo,
             float* __restrict__ Fo) {
  const int Kdim = 1024;
  __shared__ bf16 As[128 * 64];
  __shared__ bf16 Bs[128 * 64];
  const int tid = threadIdx.x;
  const int wid = tid >> 6, lane = tid & 63;
  const int m0 = blockIdx.x * 128;
  const int n0 = blockIdx.y * 128;
  const int wrow = (wid >> 1) * 64, wcol = (wid & 1) * 64;

  f32x4 acc[4][4];
#pragma unroll
  for (int rb = 0; rb < 4; ++rb)
#pragma unroll
    for (int cb = 0; cb < 4; ++cb)
      acc[rb][cb] = (f32x4){0.f, 0.f, 0.f, 0.f};

  const int lr = lane >> 3;
  const int lc = (lane & 7) * 8;
  const int fr = lane & 15, fk = (lane >> 4) * 8;

  for (int kt = 0; kt < Kdim / 64; ++kt) {
    __syncthreads();
#pragma unroll
    for (int t = 0; t < 4; ++t) {
      int i = wid * 4 + t;
      int row = i * 8 + lr;
      load_lds16(A + (size_t)(m0 + row) * Kdim + kt * 64 + lc, (char*)As + i * 1024);
      load_lds16(BT + (size_t)(n0 + row) * Kdim + kt * 64 + lc, (char*)Bs + i * 1024);
    }
    __syncthreads();

    short8 af[4][2], bf_[4][2];
#pragma unroll
    for (int rb = 0; rb < 4; ++rb)
#pragma unroll
      for (int kk = 0; kk < 2; ++kk) {
        af[rb][kk] = *(const short8*)&As[(wrow + rb * 16 + fr) * 64 + kk * 32 + fk];
        bf_[rb][kk] = *(const short8*)&Bs[(wcol + rb * 16 + fr) * 64 + kk * 32 + fk];
      }
#pragma unroll
    for (int rb = 0; rb < 4; ++rb)
#pragma unroll
      for (int cb = 0; cb < 4; ++cb)
#pragma unroll
        for (int kk = 0; kk < 2; ++kk)
          acc[rb][cb] = __builtin_amdgcn_mfma_f32_16x16x32_bf16(
              af[rb][kk], bf_[cb][kk], acc[rb][cb], 0, 0, 0);
  }

  const int fg = (lane >> 4) * 4;
  float bv[4];
#pragma unroll
  for (int cb = 0; cb < 4; ++cb) bv[cb] = bias[n0 + wcol + cb * 16 + fr];

  if (EPI == 0) {
#pragma unroll
    for (int rb = 0; rb < 4; ++rb) {
      int r0 = m0 + wrow + rb * 16 + fg;
#pragma unroll
      for (int cb = 0; cb < 4; ++cb) {
        int n = n0 + wcol + cb * 16 + fr;
        int part = n >> 10;
        int d = n & 1023;
        int h = d >> 6, hd = d & 63;
#pragma unroll
        for (int j = 0; j < 4; ++j) {
          int m = r0 + j;
          int b = m >> 11, s = m & 2047;
          size_t bh = (size_t)(b * NH + h);
          float vv = acc[rb][cb][j] + bv[cb];
          if (part == 0) {
            Qo[(bh * SEQ + s) * HD + hd] = __float2bfloat16(vv * QSCALE);
          } else if (part == 1) {
            Ko[(bh * SEQ + s) * HD + hd] = __float2bfloat16(vv);
          } else {
            Vo[(bh * HD + hd) * SEQ + s] = __float2bfloat16(vv);
          }
        }
      }
    }
  } else {
#pragma unroll
    for (int rb = 0; rb < 4; ++rb) {
      int r0 = m0 + wrow + rb * 16 + fg;
#pragma unroll
      for (int cb = 0; cb < 4; ++cb) {
        int n = n0 + wcol + cb * 16 + fr;
#pragma unroll
        for (int j = 0; j < 4; ++j)
          Fo[(size_t)(r0 + j) * HID + n] = acc[rb][cb][j] + bv[cb];
      }
    }
  }
}

// ---------------- causal flash attention, swapped-operand 32x32 ----------------
// grid 512 flat: qt = 15 - idx/32 (heavy first), bh = idx%32.
// 4 waves x 32 q rows = 128 rows/block. KVBLK=64. Sᵀ=mfma(K,Q): q lane-local.
__global__ __launch_bounds__(256, 2)
void attn_kernel(const bf16* __restrict__ Q, const bf16* __restrict__ K,
                 const bf16* __restrict__ VT, bf16* __restrict__ ctx) {
  __shared__ char smem[16384];           // Ks [64][64] | Vs [64][64], XOR-swizzled
  const int tid = threadIdx.x, wid = tid >> 6, lane = tid & 63;
  const int idx = blockIdx.x;
  const int qt = 15 - (idx >> 5);
  const int bh = idx & 31;
  const int b = bh >> 4, h = bh & 15;
  const size_t base = (size_t)bh * SEQ * HD;
  const int q0 = qt * 128 + wid * 32;

  const int fr = lane & 31, hi = lane >> 5;
  const int lr = lane >> 3;              // 0..7
  const int cc = lane & 7;
  const int qg = q0 + fr;

  // Q fragments (B operand), hoisted. Q is pre-scaled by QSCALE (incl. log2e).
  short8 qf[4];
  const bf16* qp = Q + base + (size_t)qg * HD;
#pragma unroll
  for (int kc = 0; kc < 4; ++kc)
    qf[kc] = *(const short8*)(qp + kc * 16 + hi * 8);

  f32x16 oc[2];
#pragma unroll
  for (int da = 0; da < 2; ++da)
#pragma unroll
    for (int r = 0; r < 16; ++r) oc[da][r] = 0.f;
  float mrun = -1e30f, lrun = 0.f;

  const int nkv = qt * 2 + 2;
  for (int kv = 0; kv < nkv; ++kv) {
    const int kv0 = kv * 64;
    __syncthreads();
    {
      const int gc = (cc ^ lr) * 8;  // pre-swizzled source chunk
#pragma unroll
      for (int t = 0; t < 2; ++t) {
        int i = wid * 2 + t;
        load_lds16(K + base + (size_t)(kv0 + i * 8 + lr) * HD + gc, smem + i * 1024);
        load_lds16(VT + base + (size_t)(i * 8 + lr) * SEQ + kv0 + gc,
                   smem + 8192 + i * 1024);
      }
    }
    __syncthreads();
    if (kv0 > q0 + 31) continue;

    // S^T[kv][q] = K · Q^T  (A = K rows, B = Q rows)
    f32x16 sa[2];
#pragma unroll
    for (int kb = 0; kb < 2; ++kb) {
#pragma unroll
      for (int r = 0; r < 16; ++r) sa[kb][r] = 0.f;
      const int row = kb * 32 + fr;
      const int swz = (row & 7) << 4;
#pragma unroll
      for (int kc = 0; kc < 4; ++kc) {
        short8 kf = *(const short8*)(smem + row * 128 + ((kc * 32 + hi * 16) ^ swz));
        sa[kb] = __builtin_amdgcn_mfma_f32_32x32x16_bf16(kf, qf[kc], sa[kb], 0, 0, 0);
      }
    }

    // causal mask (only boundary tiles need it)
    if (kv0 + 63 > q0) {
#pragma unroll
      for (int kb = 0; kb < 2; ++kb)
#pragma unroll
        for (int r = 0; r < 16; ++r) {
          int kvg = kv0 + kb * 32 + (r & 3) + 8 * (r >> 2) + 4 * hi;
          sa[kb][r] = (kvg > qg) ? -1e30f : sa[kb][r];
        }
    }

    // online softmax, stats per lane (its q)
    float mx = -1e30f;
#pragma unroll
    for (int kb = 0; kb < 2; ++kb)
#pragma unroll
      for (int r = 0; r < 16; ++r) mx = fmaxf(mx, sa[kb][r]);
    mx = fmaxf(mx, __shfl_xor(mx, 32));

    if (__any(mx > mrun + 8.f)) {       // defer-max (T13)
      float mn = fmaxf(mrun, mx);
      float fac = __builtin_exp2f(mrun - mn);
      lrun *= fac;
#pragma unroll
      for (int da = 0; da < 2; ++da)
#pragma unroll
        for (int r = 0; r < 16; ++r) oc[da][r] *= fac;
      mrun = mn;
    }
    float rs = 0.f;
#pragma unroll
    for (int kb = 0; kb < 2; ++kb)
#pragma unroll
      for (int r = 0; r < 16; ++r) {
        float e = __builtin_exp2f(sa[kb][r] - mrun);
        sa[kb][r] = e;
        rs += e;
      }
    rs += __shfl_xor(rs, 32);
    lrun += rs;

    // P -> bf16 PV B-fragments in-register.
    // pk[kb][i] holds kv = kb*32 + 8*(i>>1) + 2*(i&1) + 4*hi + {0,1}.
    // Needed word w of slice ks: kv = ks*16 + hi*8 + 2w + {0,1}.
    // Exchange via shfl_xor(32) (unambiguous semantics) + hi-select.
    unsigned pk[2][8], px[2][8];
#pragma unroll
    for (int kb = 0; kb < 2; ++kb) {
#pragma unroll
      for (int i = 0; i < 8; ++i)
        pk[kb][i] = cvt_pk_bf16(sa[kb][2 * i], sa[kb][2 * i + 1]);
#pragma unroll
      for (int i = 0; i < 8; ++i)
        px[kb][i] = (unsigned)__shfl_xor((int)pk[kb][i], 32);
    }

    // ctx^T[d][q] += V^T · P  (A = V^T rows=d, B = P rows=q)
#pragma unroll
    for (int da = 0; da < 2; ++da) {
      const int row = da * 32 + fr;
      const int swz = (row & 7) << 4;
#pragma unroll
      for (int ks = 0; ks < 4; ++ks) {
        short8 vf = *(const short8*)(smem + 8192 + row * 128 +
                                     ((ks * 32 + hi * 16) ^ swz));
        const int kb = ks >> 1, g = (ks & 1) * 4;
        union { unsigned u[4]; short8 s; } pf;
        pf.u[0] = hi ? px[kb][g + 2] : pk[kb][g + 0];
        pf.u[1] = hi ? px[kb][g + 3] : pk[kb][g + 1];
        pf.u[2] = hi ? pk[kb][g + 2] : px[kb][g + 0];
        pf.u[3] = hi ? pk[kb][g + 3] : px[kb][g + 1];
        oc[da] = __builtin_amdgcn_mfma_f32_32x32x16_bf16(vf, pf.s, oc[da], 0, 0, 0);
      }
    }
  }

  // ---------------- epilogue: per-wave LDS transpose, coalesced store ----------------
  __syncthreads();                       // all waves done with Ks/Vs
  const float inv = 1.f / lrun;
  char* ep = smem + wid * 4096;          // [32 q][64 d] bf16, swizzled
#pragma unroll
  for (int da = 0; da < 2; ++da)
#pragma unroll
    for (int rg = 0; rg < 4; ++rg) {
      int d0 = da * 64 + rg * 16 + hi * 8;  // byte offset of d within row
      unsigned w0 = pack2bf(oc[da][rg * 4 + 0] * inv, oc[da][rg * 4 + 1] * inv);
      unsigned w1 = pack2bf(oc[da][rg * 4 + 2] * inv, oc[da][rg * 4 + 3] * inv);
      uint2 wv; wv.x = w0; wv.y = w1;
      *(uint2*)(ep + fr * 128 + (d0 ^ ((fr & 7) << 4))) = wv;
    }
  // per-wave data only -> same-wave lgkmcnt ordering suffices
#pragma unroll
  for (int p = 0; p < 4; ++p) {
    int qr = p * 8 + lr;
    uint4 v = *(const uint4*)(ep + qr * 128 + ((cc * 16) ^ ((qr & 7) << 4)));
    int s = q0 + qr;
    *(uint4*)(ctx + (size_t)(b * SEQ + s) * HID + h * 64 + cc * 8) = v;
  }
}

// ---------------- launch ----------------
extern "C" void kernel_launch(void* const* d_in, const int* in_sizes, int n_in,
                              void* d_out, int out_size, void* d_ws, size_t ws_size,
                              hipStream_t stream) {
  const float* x      = (const float*)d_in[0];
  const float* W_attn = (const float*)d_in[1];
  const float* b_attn = (const float*)d_in[2];
  const float* W_proj = (const float*)d_in[3];
  const float* b_proj = (const float*)d_in[4];
  float* out = (float*)d_out;

  char* ws = (char*)d_ws;
  const size_t MB = 1u << 20;
  bf16* xb   = (bf16*)(ws + 0);
  bf16* WTa  = (bf16*)(ws + 8 * MB);
  bf16* WTp  = (bf16*)(ws + 14 * MB);
  bf16* Qw   = (bf16*)(ws + 16 * MB);
  bf16* Kw   = (bf16*)(ws + 24 * MB);
  bf16* VTw  = (bf16*)(ws + 32 * MB);
  bf16* ctxb = (bf16*)(ws + 40 * MB);

  cvt_f32_to_bf16<<<(M_TOT * HID / 4 + 255) / 256, 256, 0, stream>>>(x, xb, M_TOT * HID / 4);
  transpose_cvt<<<dim3(3 * HID / 32, HID / 32), dim3(32, 8), 0, stream>>>(W_attn, WTa, HID, 3 * HID);
  transpose_cvt<<<dim3(HID / 32, HID / 32), dim3(32, 8), 0, stream>>>(W_proj, WTp, HID, HID);

  gemm128<0><<<dim3(M_TOT / 128, 3 * HID / 128), 256, 0, stream>>>(
      xb, WTa, b_attn, Qw, Kw, VTw, nullptr);

  attn_kernel<<<dim3(512), 256, 0, stream>>>(Qw, Kw, VTw, ctxb);

  gemm128<1><<<dim3(M_TOT / 128, HID / 128), 256, 0, stream>>>(
      ctxb, WTp, b_proj, nullptr, nullptr, nullptr, out);
}

// Round 4
// 130.960 us; speedup vs baseline: 1.6228x; 1.0485x over previous
//
#include <hip/hip_runtime.h>
#include <hip/hip_bf16.h>
#include <stdint.h>

#define HID 1024
#define NH 16
#define HD 64
#define SEQ 2048
#define BATCH 2
#define M_TOT 4096
#define QSCALE 0.18033688011112042f  /* 0.125 * log2(e) */

typedef __attribute__((ext_vector_type(8))) short short8;
typedef __attribute__((ext_vector_type(4))) float f32x4;
typedef __attribute__((ext_vector_type(16))) float f32x16;
typedef __hip_bfloat16 bf16;

__device__ __forceinline__ void load_lds16(const void* g, void* l) {
  __builtin_amdgcn_global_load_lds(
      (const __attribute__((address_space(1))) unsigned int*)g,
      (__attribute__((address_space(3))) unsigned int*)l, 16, 0, 0);
}

__device__ __forceinline__ unsigned short f2bf_bits(float f) {
  __hip_bfloat16 h = __float2bfloat16(f);
  return *reinterpret_cast<unsigned short*>(&h);
}
__device__ __forceinline__ unsigned pack2bf(float a, float b) {
  return (unsigned)f2bf_bits(a) | ((unsigned)f2bf_bits(b) << 16);
}
__device__ __forceinline__ unsigned cvt_pk_bf16(float a, float b) {
  unsigned r;
  asm("v_cvt_pk_bf16_f32 %0, %1, %2" : "=v"(r) : "v"(a), "v"(b));
  return r;
}

// ---------------- prep kernels ----------------
__global__ void cvt_f32_to_bf16(const float* __restrict__ in,
                                bf16* __restrict__ out, int n4) {
  int i = blockIdx.x * blockDim.x + threadIdx.x;
  if (i >= n4) return;
  float4 v = reinterpret_cast<const float4*>(in)[i];
  ushort4 o;
  o.x = f2bf_bits(v.x); o.y = f2bf_bits(v.y);
  o.z = f2bf_bits(v.z); o.w = f2bf_bits(v.w);
  reinterpret_cast<ushort4*>(out)[i] = o;
}

__global__ void transpose_cvt(const float* __restrict__ W,
                              bf16* __restrict__ WT, int K, int N) {
  __shared__ float tile[32][33];
  int n0 = blockIdx.x * 32, k0 = blockIdx.y * 32;
  int tx = threadIdx.x, ty = threadIdx.y;  // 32 x 8
#pragma unroll
  for (int i = 0; i < 32; i += 8)
    tile[ty + i][tx] = W[(size_t)(k0 + ty + i) * N + n0 + tx];
  __syncthreads();
#pragma unroll
  for (int i = 0; i < 32; i += 8)
    WT[(size_t)(n0 + ty + i) * K + k0 + tx] = __float2bfloat16(tile[tx][ty + i]);
}

// ---------------- GEMM: C[M][N] = A[M][K] * BT[N][K]^T + bias ----------------
template <int EPI>
__global__ __launch_bounds__(256, 2)
void gemm128(const bf16* __restrict__ A, const bf16* __restrict__ BT,
             const float* __restrict__ bias,
             bf16* __restrict__ Qo, bf16* __restrict__ Ko, bf16* __restrict__ Vo,
             float* __restrict__ Fo) {
  const int Kdim = 1024;
  __shared__ bf16 As[128 * 64];
  __shared__ bf16 Bs[128 * 64];
  const int tid = threadIdx.x;
  const int wid = tid >> 6, lane = tid & 63;
  const int m0 = blockIdx.x * 128;
  const int n0 = blockIdx.y * 128;
  const int wrow = (wid >> 1) * 64, wcol = (wid & 1) * 64;

  f32x4 acc[4][4];
#pragma unroll
  for (int rb = 0; rb < 4; ++rb)
#pragma unroll
    for (int cb = 0; cb < 4; ++cb)
      acc[rb][cb] = (f32x4){0.f, 0.f, 0.f, 0.f};

  const int lr = lane >> 3;
  const int lc = (lane & 7) * 8;
  const int fr = lane & 15, fk = (lane >> 4) * 8;

  for (int kt = 0; kt < Kdim / 64; ++kt) {
    __syncthreads();
#pragma unroll
    for (int t = 0; t < 4; ++t) {
      int i = wid * 4 + t;
      int row = i * 8 + lr;
      load_lds16(A + (size_t)(m0 + row) * Kdim + kt * 64 + lc, (char*)As + i * 1024);
      load_lds16(BT + (size_t)(n0 + row) * Kdim + kt * 64 + lc, (char*)Bs + i * 1024);
    }
    __syncthreads();

    short8 af[4][2], bf_[4][2];
#pragma unroll
    for (int rb = 0; rb < 4; ++rb)
#pragma unroll
      for (int kk = 0; kk < 2; ++kk) {
        af[rb][kk] = *(const short8*)&As[(wrow + rb * 16 + fr) * 64 + kk * 32 + fk];
        bf_[rb][kk] = *(const short8*)&Bs[(wcol + rb * 16 + fr) * 64 + kk * 32 + fk];
      }
#pragma unroll
    for (int rb = 0; rb < 4; ++rb)
#pragma unroll
      for (int cb = 0; cb < 4; ++cb)
#pragma unroll
        for (int kk = 0; kk < 2; ++kk)
          acc[rb][cb] = __builtin_amdgcn_mfma_f32_16x16x32_bf16(
              af[rb][kk], bf_[cb][kk], acc[rb][cb], 0, 0, 0);
  }

  const int fg = (lane >> 4) * 4;
  float bv[4];
#pragma unroll
  for (int cb = 0; cb < 4; ++cb) bv[cb] = bias[n0 + wcol + cb * 16 + fr];

  if (EPI == 0) {
#pragma unroll
    for (int rb = 0; rb < 4; ++rb) {
      int r0 = m0 + wrow + rb * 16 + fg;
#pragma unroll
      for (int cb = 0; cb < 4; ++cb) {
        int n = n0 + wcol + cb * 16 + fr;
        int part = n >> 10;
        int d = n & 1023;
        int h = d >> 6, hd = d & 63;
#pragma unroll
        for (int j = 0; j < 4; ++j) {
          int m = r0 + j;
          int b = m >> 11, s = m & 2047;
          size_t bh = (size_t)(b * NH + h);
          float vv = acc[rb][cb][j] + bv[cb];
          if (part == 0) {
            Qo[(bh * SEQ + s) * HD + hd] = __float2bfloat16(vv * QSCALE);
          } else if (part == 1) {
            Ko[(bh * SEQ + s) * HD + hd] = __float2bfloat16(vv);
          } else {
            Vo[(bh * HD + hd) * SEQ + s] = __float2bfloat16(vv);
          }
        }
      }
    }
  } else {
#pragma unroll
    for (int rb = 0; rb < 4; ++rb) {
      int r0 = m0 + wrow + rb * 16 + fg;
#pragma unroll
      for (int cb = 0; cb < 4; ++cb) {
        int n = n0 + wcol + cb * 16 + fr;
#pragma unroll
        for (int j = 0; j < 4; ++j)
          Fo[(size_t)(r0 + j) * HID + n] = acc[rb][cb][j] + bv[cb];
      }
    }
  }
}

// ---------------- causal flash attention, swapped-operand 32x32 ----------------
// grid 512 flat, pair-balanced: idx<256 -> qt=15-(idx>>5) (heavy), else
// qt=(idx-256)>>5 (light); co-resident pair (i, i+256) sums to 34 kv-iters.
// 4 waves x 32 q rows. KVBLK=64. Double-buffered LDS, stage-before-compute.
__global__ __launch_bounds__(256, 2)
void attn_kernel(const bf16* __restrict__ Q, const bf16* __restrict__ K,
                 const bf16* __restrict__ VT, bf16* __restrict__ ctx) {
  __shared__ char smem[32768];   // buf b: K at b*16384, V at b*16384+8192
  const int tid = threadIdx.x, wid = tid >> 6, lane = tid & 63;
  const int idx = blockIdx.x;
  const int qt = (idx < 256) ? (15 - (idx >> 5)) : ((idx - 256) >> 5);
  const int bh = idx & 31;
  const int b = bh >> 4, h = bh & 15;
  const size_t base = (size_t)bh * SEQ * HD;
  const int q0 = qt * 128 + wid * 32;

  const int fr = lane & 31, hi = lane >> 5;
  const int lr = lane >> 3;              // 0..7
  const int cc = lane & 7;
  const int qg = q0 + fr;
  const int gc = (cc ^ lr) * 8;          // pre-swizzled source chunk

  // Q fragments (B operand), hoisted. Q is pre-scaled by QSCALE (incl. log2e).
  short8 qf[4];
  const bf16* qp = Q + base + (size_t)qg * HD;
#pragma unroll
  for (int kc = 0; kc < 4; ++kc)
    qf[kc] = *(const short8*)(qp + kc * 16 + hi * 8);

  f32x16 oc[2];
#pragma unroll
  for (int da = 0; da < 2; ++da)
#pragma unroll
    for (int r = 0; r < 16; ++r) oc[da][r] = 0.f;
  float mrun = -1e30f, lrun = 0.f;

  const int nkv = qt * 2 + 2;

  // prologue: stage kv=0 into buf 0
  {
#pragma unroll
    for (int t = 0; t < 2; ++t) {
      int i = wid * 2 + t;
      load_lds16(K + base + (size_t)(i * 8 + lr) * HD + gc, smem + i * 1024);
      load_lds16(VT + base + (size_t)(i * 8 + lr) * SEQ + gc, smem + 8192 + i * 1024);
    }
  }
  __syncthreads();

  for (int kv = 0; kv < nkv; ++kv) {
    const int kv0 = kv * 64;
    const int cur = kv & 1;
    char* sb = smem + cur * 16384;

    // stage next tile into the other buffer (its loads drain at the
    // end-of-iter barrier, i.e. after the whole compute phase)
    if (kv + 1 < nkv) {
      const int nv0 = (kv + 1) * 64;
      char* nb = smem + (1 - cur) * 16384;
#pragma unroll
      for (int t = 0; t < 2; ++t) {
        int i = wid * 2 + t;
        load_lds16(K + base + (size_t)(nv0 + i * 8 + lr) * HD + gc, nb + i * 1024);
        load_lds16(VT + base + (size_t)(i * 8 + lr) * SEQ + nv0 + gc,
                   nb + 8192 + i * 1024);
      }
    }

    if (kv0 <= q0 + 31) {
      // S^T[kv][q] = K · Q^T  (A = K rows, B = Q rows)
      f32x16 sa[2];
#pragma unroll
      for (int kb = 0; kb < 2; ++kb) {
#pragma unroll
        for (int r = 0; r < 16; ++r) sa[kb][r] = 0.f;
        const int row = kb * 32 + fr;
        const int swz = (row & 7) << 4;
#pragma unroll
        for (int kc = 0; kc < 4; ++kc) {
          short8 kf = *(const short8*)(sb + row * 128 + ((kc * 32 + hi * 16) ^ swz));
          sa[kb] = __builtin_amdgcn_mfma_f32_32x32x16_bf16(kf, qf[kc], sa[kb], 0, 0, 0);
        }
      }

      // causal mask (only boundary tiles need it)
      if (kv0 + 63 > q0) {
#pragma unroll
        for (int kb = 0; kb < 2; ++kb)
#pragma unroll
          for (int r = 0; r < 16; ++r) {
            int kvg = kv0 + kb * 32 + (r & 3) + 8 * (r >> 2) + 4 * hi;
            sa[kb][r] = (kvg > qg) ? -1e30f : sa[kb][r];
          }
      }

      // online softmax, stats per lane (its q)
      float mx = -1e30f;
#pragma unroll
      for (int kb = 0; kb < 2; ++kb)
#pragma unroll
        for (int r = 0; r < 16; ++r) mx = fmaxf(mx, sa[kb][r]);
      mx = fmaxf(mx, __shfl_xor(mx, 32));

      if (__any(mx > mrun + 8.f)) {       // defer-max (T13)
        float mn = fmaxf(mrun, mx);
        float fac = __builtin_exp2f(mrun - mn);
        lrun *= fac;
#pragma unroll
        for (int da = 0; da < 2; ++da)
#pragma unroll
          for (int r = 0; r < 16; ++r) oc[da][r] *= fac;
        mrun = mn;
      }
      float rs = 0.f;
#pragma unroll
      for (int kb = 0; kb < 2; ++kb)
#pragma unroll
        for (int r = 0; r < 16; ++r) {
          float e = __builtin_exp2f(sa[kb][r] - mrun);
          sa[kb][r] = e;
          rs += e;
        }
      rs += __shfl_xor(rs, 32);
      lrun += rs;

      // P -> bf16 PV B-fragments in-register.
      // pk[kb][i] holds kv = kb*32 + 8*(i>>1) + 2*(i&1) + 4*hi + {0,1}.
      // Needed word w of slice ks: kv = ks*16 + hi*8 + 2w + {0,1}.
      unsigned pk[2][8], px[2][8];
#pragma unroll
      for (int kb = 0; kb < 2; ++kb) {
#pragma unroll
        for (int i = 0; i < 8; ++i)
          pk[kb][i] = cvt_pk_bf16(sa[kb][2 * i], sa[kb][2 * i + 1]);
#pragma unroll
        for (int i = 0; i < 8; ++i)
          px[kb][i] = (unsigned)__shfl_xor((int)pk[kb][i], 32);
      }

      // ctx^T[d][q] += V^T · P  (A = V^T rows=d, B = P rows=q)
#pragma unroll
      for (int da = 0; da < 2; ++da) {
        const int row = da * 32 + fr;
        const int swz = (row & 7) << 4;
#pragma unroll
        for (int ks = 0; ks < 4; ++ks) {
          short8 vf = *(const short8*)(sb + 8192 + row * 128 +
                                       ((ks * 32 + hi * 16) ^ swz));
          const int kb = ks >> 1, g = (ks & 1) * 4;
          union { unsigned u[4]; short8 s; } pf;
          pf.u[0] = hi ? px[kb][g + 2] : pk[kb][g + 0];
          pf.u[1] = hi ? px[kb][g + 3] : pk[kb][g + 1];
          pf.u[2] = hi ? pk[kb][g + 2] : px[kb][g + 0];
          pf.u[3] = hi ? pk[kb][g + 3] : px[kb][g + 1];
          oc[da] = __builtin_amdgcn_mfma_f32_32x32x16_bf16(vf, pf.s, oc[da], 0, 0, 0);
        }
      }
    }

    __syncthreads();   // drains this iter's prefetch; buffers swap safely
  }

  // ---------------- epilogue: per-wave LDS transpose, coalesced store ----------------
  const float inv = 1.f / lrun;
  char* ep = smem + wid * 4096;          // [32 q][64 d] bf16, swizzled
#pragma unroll
  for (int da = 0; da < 2; ++da)
#pragma unroll
    for (int rg = 0; rg < 4; ++rg) {
      int d0 = da * 64 + rg * 16 + hi * 8;  // byte offset of d within row
      unsigned w0 = pack2bf(oc[da][rg * 4 + 0] * inv, oc[da][rg * 4 + 1] * inv);
      unsigned w1 = pack2bf(oc[da][rg * 4 + 2] * inv, oc[da][rg * 4 + 3] * inv);
      uint2 wv; wv.x = w0; wv.y = w1;
      *(uint2*)(ep + fr * 128 + (d0 ^ ((fr & 7) << 4))) = wv;
    }
  // per-wave data only -> same-wave lgkmcnt ordering suffices
#pragma unroll
  for (int p = 0; p < 4; ++p) {
    int qr = p * 8 + lr;
    uint4 v = *(const uint4*)(ep + qr * 128 + ((cc * 16) ^ ((qr & 7) << 4)));
    int s = q0 + qr;
    *(uint4*)(ctx + (size_t)(b * SEQ + s) * HID + h * 64 + cc * 8) = v;
  }
}

// ---------------- launch ----------------
extern "C" void kernel_launch(void* const* d_in, const int* in_sizes, int n_in,
                              void* d_out, int out_size, void* d_ws, size_t ws_size,
                              hipStream_t stream) {
  const float* x      = (const float*)d_in[0];
  const float* W_attn = (const float*)d_in[1];
  const float* b_attn = (const float*)d_in[2];
  const float* W_proj = (const float*)d_in[3];
  const float* b_proj = (const float*)d_in[4];
  float* out = (float*)d_out;

  char* ws = (char*)d_ws;
  const size_t MB = 1u << 20;
  bf16* xb   = (bf16*)(ws + 0);
  bf16* WTa  = (bf16*)(ws + 8 * MB);
  bf16* WTp  = (bf16*)(ws + 14 * MB);
  bf16* Qw   = (bf16*)(ws + 16 * MB);
  bf16* Kw   = (bf16*)(ws + 24 * MB);
  bf16* VTw  = (bf16*)(ws + 32 * MB);
  bf16* ctxb = (bf16*)(ws + 40 * MB);

  cvt_f32_to_bf16<<<(M_TOT * HID / 4 + 255) / 256, 256, 0, stream>>>(x, xb, M_TOT * HID / 4);
  transpose_cvt<<<dim3(3 * HID / 32, HID / 32), dim3(32, 8), 0, stream>>>(W_attn, WTa, HID, 3 * HID);
  transpose_cvt<<<dim3(HID / 32, HID / 32), dim3(32, 8), 0, stream>>>(W_proj, WTp, HID, HID);

  gemm128<0><<<dim3(M_TOT / 128, 3 * HID / 128), 256, 0, stream>>>(
      xb, WTa, b_attn, Qw, Kw, VTw, nullptr);

  attn_kernel<<<dim3(512), 256, 0, stream>>>(Qw, Kw, VTw, ctxb);

  gemm128<1><<<dim3(M_TOT / 128, HID / 128), 256, 0, stream>>>(
      ctxb, WTp, b_proj, nullptr, nullptr, nullptr, out);
}